// Round 2
// baseline (421.719 us; speedup 1.0000x reference)
//
#include <hip/hip_runtime.h>

typedef __bf16 bf16;
typedef __attribute__((ext_vector_type(8))) __bf16 bf16x8;
typedef __attribute__((ext_vector_type(4))) float f32x4;
typedef __attribute__((ext_vector_type(4))) short s16x4;

#define HDIM 2048

__device__ __forceinline__ void glds16(const void* g, void* l) {
  __builtin_amdgcn_global_load_lds((const __attribute__((address_space(1))) void*)g,
                                   (__attribute__((address_space(3))) void*)l,
                                   16, 0, 0);
}

#define MFMA16(a, b, c) __builtin_amdgcn_mfma_f32_16x16x32_bf16(a, b, c, 0, 0, 0)

// acc[4][4] = A[rowBase:+128, :] @ B[colBase:+128, :]^T  (both row-major [2048,2048])
// A_F32 / B_F32 select fp32->bf16 convert-staging vs direct bf16 glds16 staging.
// 256 threads = 4 waves in 2x2, wave tile 64x64, BK=32.
template <bool A_F32, bool B_F32>
__device__ __forceinline__ void gemm128_core(const void* Ap, const void* Bp,
                                             int rowBase, int colBase,
                                             f32x4 acc[4][4],
                                             bf16* ldsA, bf16* ldsB) {
  const int t = threadIdx.x;
  const int w = t >> 6, l = t & 63;
  const int wr = (w >> 1) << 6;   // wave row offset within 128-tile
  const int wc = (w & 1) << 6;    // wave col offset
  const int lr = l & 15, lq = l >> 4;

  for (int mi = 0; mi < 4; mi++)
    for (int ni = 0; ni < 4; ni++)
      for (int r = 0; r < 4; r++) acc[mi][ni][r] = 0.f;

  // bf16-direct staging geometry (glds16): LDS [128][32], lane covers 16B
  const int sRow = (w << 4) + (l >> 2);
  const int sCol = (l & 3) << 3;
  // fp32-convert staging geometry: thread loads float4, writes 4 bf16
  const int fRow = t >> 3;          // 0..31 (+ issue*32)
  const int fCol = (t & 7) << 2;    // 0..28

  const bf16* gA16 = nullptr; const float* gA32 = nullptr;
  const bf16* gB16 = nullptr; const float* gB32 = nullptr;
  if constexpr (A_F32) gA32 = (const float*)Ap + (size_t)(rowBase + fRow) * HDIM + fCol;
  else                 gA16 = (const bf16*)Ap + (size_t)(rowBase + sRow) * HDIM + sCol;
  if constexpr (B_F32) gB32 = (const float*)Bp + (size_t)(colBase + fRow) * HDIM + fCol;
  else                 gB16 = (const bf16*)Bp + (size_t)(colBase + sRow) * HDIM + sCol;

  bf16* lA = ldsA + (w << 9);   // wave-uniform LDS base for glds16 (HW adds lane*16B)
  bf16* lB = ldsB + (w << 9);

  for (int k0 = 0; k0 < HDIM; k0 += 32) {
    if constexpr (A_F32) {
      for (int i = 0; i < 4; i++) {
        const float4 v = *(const float4*)(gA32 + (size_t)(i * 32) * HDIM);
        union { bf16 h[4]; s16x4 s4; } u;
        u.h[0] = (bf16)v.x; u.h[1] = (bf16)v.y; u.h[2] = (bf16)v.z; u.h[3] = (bf16)v.w;
        *(s16x4*)&ldsA[i * 1024 + t * 4] = u.s4;
      }
      gA32 += 32;
    } else {
      glds16(gA16, lA);
      glds16(gA16 + (size_t)64 * HDIM, lA + 2048);
      gA16 += 32;
    }
    if constexpr (B_F32) {
      for (int i = 0; i < 4; i++) {
        const float4 v = *(const float4*)(gB32 + (size_t)(i * 32) * HDIM);
        union { bf16 h[4]; s16x4 s4; } u;
        u.h[0] = (bf16)v.x; u.h[1] = (bf16)v.y; u.h[2] = (bf16)v.z; u.h[3] = (bf16)v.w;
        *(s16x4*)&ldsB[i * 1024 + t * 4] = u.s4;
      }
      gB32 += 32;
    } else {
      glds16(gB16, lB);
      glds16(gB16 + (size_t)64 * HDIM, lB + 2048);
      gB16 += 32;
    }
    __syncthreads();   // drains vmcnt (glds) + lgkmcnt (ds_write) -> tiles complete

    bf16x8 af[4], bfr[4];
    for (int mi = 0; mi < 4; mi++)
      af[mi] = *(const bf16x8*)&ldsA[(wr + mi * 16 + lr) * 32 + lq * 8];
    for (int ni = 0; ni < 4; ni++)
      bfr[ni] = *(const bf16x8*)&ldsB[(wc + ni * 16 + lr) * 32 + lq * 8];
    for (int mi = 0; mi < 4; mi++)
      for (int ni = 0; ni < 4; ni++)
        acc[mi][ni] = MFMA16(af[mi], bfr[ni], acc[mi][ni]);
    __syncthreads();
  }
}

// z=0: q = hs@Wq^T  (bf16 [B,H])
// z=1: k = hs@Wk^T  (bf16 [B,H])
// z=2: vT = (hs@Wv^T)^T  (bf16 [H,B] so attention V-frags are contiguous)
__global__ __launch_bounds__(256) void qkv_gemm(
    const float* __restrict__ hs, const float* __restrict__ Wq,
    const float* __restrict__ Wk, const float* __restrict__ Wv,
    bf16* __restrict__ qb, bf16* __restrict__ kb, bf16* __restrict__ vT) {
  __shared__ bf16 ldsA[128 * 32];
  __shared__ bf16 ldsB[128 * 32];
  const int z = blockIdx.z;
  const float* W = (z == 0) ? Wq : (z == 1) ? Wk : Wv;
  const int rowBase = blockIdx.y << 7, colBase = blockIdx.x << 7;
  f32x4 acc[4][4];
  gemm128_core<true, true>(hs, W, rowBase, colBase, acc, ldsA, ldsB);

  const int t = threadIdx.x;
  const int w = t >> 6, l = t & 63;
  const int wr = (w >> 1) << 6, wc = (w & 1) << 6;
  const int lr = l & 15, lq = l >> 4;

  if (z < 2) {
    bf16* outp = z ? kb : qb;
    for (int mi = 0; mi < 4; mi++)
      for (int ni = 0; ni < 4; ni++) {
        const int col = colBase + wc + ni * 16 + lr;
        const int row0 = rowBase + wr + mi * 16 + lq * 4;
        for (int r = 0; r < 4; r++)
          outp[(size_t)(row0 + r) * HDIM + col] = (bf16)acc[mi][ni][r];
      }
  } else {
    for (int mi = 0; mi < 4; mi++)
      for (int ni = 0; ni < 4; ni++) {
        const int col = colBase + wc + ni * 16 + lr;   // v column = dim index
        const int row0 = rowBase + wr + mi * 16 + lq * 4;  // batch rows
        union { bf16 h[4]; s16x4 v; } u;
        for (int r = 0; r < 4; r++) u.h[r] = (bf16)acc[mi][ni][r];
        *(s16x4*)&vT[(size_t)col * HDIM + row0] = u.v;  // 4 consecutive batch -> 8B store
      }
  }
}

// Flash attention: block = (q-tile of 128, head). 4 waves, each owns 32 q-rows.
__global__ __launch_bounds__(256, 1) void attn_kernel(
    const bf16* __restrict__ qb, const bf16* __restrict__ kb,
    const bf16* __restrict__ vT, const unsigned char* __restrict__ amask,
    bf16* __restrict__ ctx) {
  __shared__ bf16 Kl[128 * 128];           // K-tile [key][dim]; also Q staging
  __shared__ bf16 Vl[128 * 128];           // V-tile [dim][key] (from vT)
  __shared__ bf16 Pl[4 * 32 * 128];        // per-wave P round-trip (C->A layout)

  const int qt = blockIdx.x, h = blockIdx.y;
  const int t = threadIdx.x, w = t >> 6, l = t & 63;
  const int lr = l & 15, lq = l >> 4;
  const float NEG_INF = -__builtin_inff();

  // staging geometry for [128][128] bf16 tiles: 8 issues of 16 rows each
  const int sRow = (w << 2) + (l >> 4);
  const int sCol = (l & 15) << 3;

  // --- stage Q into Kl, hoist A-fragments to registers ---
  {
    const bf16* gQ = qb + (size_t)(qt * 128 + sRow) * HDIM + h * 128 + sCol;
    bf16* lb = Kl + (w << 9);
    for (int i = 0; i < 8; i++) glds16(gQ + (size_t)(i * 16) * HDIM, lb + i * 2048);
  }
  __syncthreads();
  bf16x8 aq[2][4];
  for (int mi = 0; mi < 2; mi++)
    for (int ks = 0; ks < 4; ks++)
      aq[mi][ks] = *(const bf16x8*)&Kl[(w * 32 + mi * 16 + lr) * 128 + ks * 32 + lq * 8];
  __syncthreads();

  f32x4 o[2][8];
  for (int mi = 0; mi < 2; mi++)
    for (int ni = 0; ni < 8; ni++)
      for (int r = 0; r < 4; r++) o[mi][ni][r] = 0.f;
  float m_i[2][4], l_i[2][4];
  int qrow[2][4];
  for (int mi = 0; mi < 2; mi++)
    for (int r = 0; r < 4; r++) {
      m_i[mi][r] = NEG_INF;
      l_i[mi][r] = 0.f;
      qrow[mi][r] = qt * 128 + w * 32 + mi * 16 + lq * 4 + r;
    }

  const float scl = 0.08838834764831845f;  // 1/sqrt(128), TEMPERATURE=1

  for (int kbk = 0; kbk < 16; kbk++) {
    // --- stage K-tile and V-tile ---
    {
      const bf16* gK = kb + (size_t)(kbk * 128 + sRow) * HDIM + h * 128 + sCol;
      const bf16* gV = vT + (size_t)(h * 128 + sRow) * HDIM + kbk * 128 + sCol;
      bf16* lbK = Kl + (w << 9);
      bf16* lbV = Vl + (w << 9);
      for (int i = 0; i < 8; i++) glds16(gK + (size_t)(i * 16) * HDIM, lbK + i * 2048);
      for (int i = 0; i < 8; i++) glds16(gV + (size_t)(i * 16) * HDIM, lbV + i * 2048);
    }
    __syncthreads();

    // --- S = Q @ K^T  (wave: 32 q-rows x 128 keys) ---
    f32x4 s[2][8];
    for (int mi = 0; mi < 2; mi++)
      for (int ni = 0; ni < 8; ni++)
        for (int r = 0; r < 4; r++) s[mi][ni][r] = 0.f;
    for (int ks = 0; ks < 4; ks++) {
      bf16x8 bk[8];
      for (int ni = 0; ni < 8; ni++)
        bk[ni] = *(const bf16x8*)&Kl[(ni * 16 + lr) * 128 + ks * 32 + lq * 8];
      for (int mi = 0; mi < 2; mi++)
        for (int ni = 0; ni < 8; ni++)
          s[mi][ni] = MFMA16(aq[mi][ks], bk[ni], s[mi][ni]);
    }

    // --- scale + mask + online softmax ---
    float alpha[2][4];
    for (int mi = 0; mi < 2; mi++) {
      for (int ni = 0; ni < 8; ni++) {
        const int col = kbk * 128 + ni * 16 + lr;
        const bool valid = (amask[col] != 0);
        for (int r = 0; r < 4; r++) {
          float v = s[mi][ni][r] * scl;
          if (!valid || col == qrow[mi][r]) v = NEG_INF;
          s[mi][ni][r] = v;
        }
      }
      for (int r = 0; r < 4; r++) {
        float mx = NEG_INF;
        for (int ni = 0; ni < 8; ni++) mx = fmaxf(mx, s[mi][ni][r]);
        for (int off = 1; off < 16; off <<= 1) mx = fmaxf(mx, __shfl_xor(mx, off));
        const float mold = m_i[mi][r];
        const float mnew = fmaxf(mold, mx);
        const float a = (mold == NEG_INF) ? 0.f : __expf(mold - mnew);
        float rs = 0.f;
        for (int ni = 0; ni < 8; ni++) {
          const float sv = s[mi][ni][r];
          const float p = (sv == NEG_INF) ? 0.f : __expf(sv - mnew);
          s[mi][ni][r] = p;
          rs += p;
        }
        for (int off = 1; off < 16; off <<= 1) rs += __shfl_xor(rs, off);
        l_i[mi][r] = l_i[mi][r] * a + rs;
        m_i[mi][r] = mnew;
        alpha[mi][r] = a;
      }
    }
    for (int mi = 0; mi < 2; mi++)
      for (int ni = 0; ni < 8; ni++)
        for (int r = 0; r < 4; r++) o[mi][ni][r] *= alpha[mi][r];

    // --- P: C-layout regs -> per-wave LDS (A-layout readable) ---
    bf16* pb = Pl + (w << 12);
    for (int mi = 0; mi < 2; mi++)
      for (int ni = 0; ni < 8; ni++)
        for (int r = 0; r < 4; r++)
          pb[(mi * 16 + lq * 4 + r) * 128 + ni * 16 + lr] = (bf16)s[mi][ni][r];
    __syncthreads();   // safety: P writes visible before A-frag reads

    // --- O += P @ V  (K-dim = 128 keys) ---
    for (int ks = 0; ks < 4; ks++) {
      bf16x8 bv[8];
      for (int ni = 0; ni < 8; ni++)
        bv[ni] = *(const bf16x8*)&Vl[(ni * 16 + lr) * 128 + ks * 32 + lq * 8];
      for (int mi = 0; mi < 2; mi++) {
        const bf16x8 ap = *(const bf16x8*)&pb[(mi * 16 + lr) * 128 + ks * 32 + lq * 8];
        for (int ni = 0; ni < 8; ni++) o[mi][ni] = MFMA16(ap, bv[ni], o[mi][ni]);
      }
    }
    __syncthreads();
  }

  // --- epilogue: ctx = O / l  (fully-masked row -> 0, matches nan_to_num) ---
  for (int mi = 0; mi < 2; mi++)
    for (int ni = 0; ni < 8; ni++)
      for (int r = 0; r < 4; r++) {
        const int row = qrow[mi][r];
        const int col = h * 128 + ni * 16 + lr;
        const float li = l_i[mi][r];
        const float val = (li > 0.f) ? o[mi][ni][r] / li : 0.f;
        ctx[(size_t)row * HDIM + col] = (bf16)val;
      }
}

// out = fp32( hs + sigmoid(scale) * (ctx @ Wo^T) )
__global__ __launch_bounds__(256) void out_gemm(
    const bf16* __restrict__ ctx, const float* __restrict__ Wo,
    const float* __restrict__ hs, const float* __restrict__ scale_p,
    float* __restrict__ outp) {
  __shared__ bf16 ldsA[128 * 32];
  __shared__ bf16 ldsB[128 * 32];
  const int rowBase = blockIdx.y << 7, colBase = blockIdx.x << 7;
  f32x4 acc[4][4];
  gemm128_core<false, true>(ctx, Wo, rowBase, colBase, acc, ldsA, ldsB);

  const float sp = scale_p[0];
  const float sig = 1.0f / (1.0f + __expf(-sp));

  const int t = threadIdx.x;
  const int w = t >> 6, l = t & 63;
  const int wr = (w >> 1) << 6, wc = (w & 1) << 6;
  const int lr = l & 15, lq = l >> 4;
  for (int mi = 0; mi < 4; mi++)
    for (int ni = 0; ni < 4; ni++) {
      const int col = colBase + wc + ni * 16 + lr;
      const int row0 = rowBase + wr + mi * 16 + lq * 4;
      for (int r = 0; r < 4; r++) {
        const size_t idx = (size_t)(row0 + r) * HDIM + col;
        outp[idx] = hs[idx] + sig * acc[mi][ni][r];
      }
    }
}

extern "C" void kernel_launch(void* const* d_in, const int* in_sizes, int n_in,
                              void* d_out, int out_size, void* d_ws, size_t ws_size,
                              hipStream_t stream) {
  const float* hs = (const float*)d_in[0];
  const unsigned char* amask = (const unsigned char*)d_in[1];
  const float* Wq = (const float*)d_in[2];
  const float* Wk = (const float*)d_in[3];
  const float* Wv = (const float*)d_in[4];
  const float* Wo = (const float*)d_in[5];
  const float* scale_p = (const float*)d_in[6];
  float* outp = (float*)d_out;

  bf16* qb = (bf16*)d_ws;                      // 8 MB each, 32 MB total
  bf16* kb = qb + (size_t)HDIM * HDIM;
  bf16* vT = kb + (size_t)HDIM * HDIM;
  bf16* ctx = vT + (size_t)HDIM * HDIM;

  qkv_gemm<<<dim3(16, 16, 3), 256, 0, stream>>>(hs, Wq, Wk, Wv, qb, kb, vT);
  attn_kernel<<<dim3(16, 16), 256, 0, stream>>>(qb, kb, vT, amask, ctx);
  out_gemm<<<dim3(16, 16), 256, 0, stream>>>(ctx, Wo, hs, scale_p, outp);
}

// Round 3
// 299.068 us; speedup vs baseline: 1.4101x; 1.4101x over previous
//
#include <hip/hip_runtime.h>

typedef __bf16 bf16;
typedef __attribute__((ext_vector_type(8))) __bf16 bf16x8;
typedef __attribute__((ext_vector_type(4))) float f32x4;
typedef __attribute__((ext_vector_type(4))) short s16x4;

#define HDIM 2048

__device__ __forceinline__ void glds16(const void* g, void* l) {
  __builtin_amdgcn_global_load_lds((const __attribute__((address_space(1))) void*)g,
                                   (__attribute__((address_space(3))) void*)l,
                                   16, 0, 0);
}

#define MFMA16(a, b, c) __builtin_amdgcn_mfma_f32_16x16x32_bf16(a, b, c, 0, 0, 0)

// fp32 -> bf16 bulk convert: grid (1024, 5); each z converts one 4M-elem tensor.
__global__ __launch_bounds__(256) void cvt5(
    const float* __restrict__ s0, const float* __restrict__ s1,
    const float* __restrict__ s2, const float* __restrict__ s3,
    const float* __restrict__ s4,
    bf16* __restrict__ d0, bf16* __restrict__ d1, bf16* __restrict__ d2,
    bf16* __restrict__ d3, bf16* __restrict__ d4) {
  const float* s; bf16* d;
  switch (blockIdx.y) {
    case 0: s = s0; d = d0; break;
    case 1: s = s1; d = d1; break;
    case 2: s = s2; d = d2; break;
    case 3: s = s3; d = d3; break;
    default: s = s4; d = d4; break;
  }
  const size_t base = (size_t)blockIdx.x * 4096 + (threadIdx.x << 2);
  for (int i = 0; i < 4; i++) {
    const float4 v = *(const float4*)(s + base + i * 1024);
    union { bf16 h[4]; s16x4 s4v; } u;
    u.h[0] = (bf16)v.x; u.h[1] = (bf16)v.y; u.h[2] = (bf16)v.z; u.h[3] = (bf16)v.w;
    *(s16x4*)(d + base + i * 1024) = u.s4v;
  }
}

// acc[4][4] = A[rowBase:+128, :] @ B[colBase:+128, :]^T, bf16 row-major [2048,2048].
// m97 structure: glds16 width-16 staging, BK=32, 4 waves in 2x2, wave tile 64x64.
__device__ __forceinline__ void gemm128_core(const bf16* __restrict__ A,
                                             const bf16* __restrict__ B,
                                             int rowBase, int colBase,
                                             f32x4 acc[4][4],
                                             bf16* ldsA, bf16* ldsB) {
  const int t = threadIdx.x;
  const int w = t >> 6, l = t & 63;
  const int wr = (w >> 1) << 6, wc = (w & 1) << 6;
  const int lr = l & 15, lq = l >> 4;

  for (int mi = 0; mi < 4; mi++)
    for (int ni = 0; ni < 4; ni++)
      for (int r = 0; r < 4; r++) acc[mi][ni][r] = 0.f;

  const int sRow = (w << 4) + (l >> 2);   // 0..63
  const int sCol = (l & 3) << 3;          // 0,8,16,24
  const bf16* gA = A + (size_t)(rowBase + sRow) * HDIM + sCol;
  const bf16* gB = B + (size_t)(colBase + sRow) * HDIM + sCol;
  bf16* lA = ldsA + (w << 9);   // wave-uniform base; HW adds lane*16B
  bf16* lB = ldsB + (w << 9);

  for (int k0 = 0; k0 < HDIM; k0 += 32) {
    glds16(gA, lA);
    glds16(gA + (size_t)64 * HDIM, lA + 2048);
    glds16(gB, lB);
    glds16(gB + (size_t)64 * HDIM, lB + 2048);
    gA += 32; gB += 32;
    __syncthreads();

    bf16x8 af[4], bfr[4];
    for (int mi = 0; mi < 4; mi++)
      af[mi] = *(const bf16x8*)&ldsA[(wr + mi * 16 + lr) * 32 + lq * 8];
    for (int ni = 0; ni < 4; ni++)
      bfr[ni] = *(const bf16x8*)&ldsB[(wc + ni * 16 + lr) * 32 + lq * 8];
    for (int mi = 0; mi < 4; mi++)
      for (int ni = 0; ni < 4; ni++)
        acc[mi][ni] = MFMA16(af[mi], bfr[ni], acc[mi][ni]);
    __syncthreads();
  }
}

// z=0: q = hs@Wq^T; z=1: k = hs@Wk^T; z=2: vT = (hs@Wv^T)^T  (all bf16)
__global__ __launch_bounds__(256) void qkv_gemm(
    const bf16* __restrict__ hs, const bf16* __restrict__ Wq,
    const bf16* __restrict__ Wk, const bf16* __restrict__ Wv,
    bf16* __restrict__ qb, bf16* __restrict__ kb, bf16* __restrict__ vT) {
  __shared__ bf16 ldsA[128 * 32];
  __shared__ bf16 ldsB[128 * 32];
  const int z = blockIdx.z;
  const bf16* W = (z == 0) ? Wq : (z == 1) ? Wk : Wv;
  const int rowBase = blockIdx.y << 7, colBase = blockIdx.x << 7;
  f32x4 acc[4][4];
  gemm128_core(hs, W, rowBase, colBase, acc, ldsA, ldsB);

  const int t = threadIdx.x;
  const int w = t >> 6, l = t & 63;
  const int wr = (w >> 1) << 6, wc = (w & 1) << 6;
  const int lr = l & 15, lq = l >> 4;

  if (z < 2) {
    bf16* outp = z ? kb : qb;
    for (int mi = 0; mi < 4; mi++)
      for (int ni = 0; ni < 4; ni++) {
        const int col = colBase + wc + ni * 16 + lr;
        const int row0 = rowBase + wr + mi * 16 + lq * 4;
        for (int r = 0; r < 4; r++)
          outp[(size_t)(row0 + r) * HDIM + col] = (bf16)acc[mi][ni][r];
      }
  } else {
    for (int mi = 0; mi < 4; mi++)
      for (int ni = 0; ni < 4; ni++) {
        const int col = colBase + wc + ni * 16 + lr;       // dim index
        const int row0 = rowBase + wr + mi * 16 + lq * 4;  // batch rows
        union { bf16 h[4]; s16x4 v; } u;
        for (int r = 0; r < 4; r++) u.h[r] = (bf16)acc[mi][ni][r];
        *(s16x4*)&vT[(size_t)col * HDIM + row0] = u.v;
      }
  }
}

// Flash attention v2: block = (q-tile of 64, head), 4 waves (16 q-rows each).
// LDS 80KB -> 2 blocks/CU (8 waves). XOR-swizzled tiles kill 16-way conflicts.
__global__ __launch_bounds__(256, 2) void attn_kernel(
    const bf16* __restrict__ qb, const bf16* __restrict__ kb,
    const bf16* __restrict__ vT, const unsigned char* __restrict__ amask,
    bf16* __restrict__ ctx) {
  __shared__ bf16 Kl[128 * 128];   // K-tile [key][dim], swizzled
  __shared__ bf16 Vl[128 * 128];   // V-tile [dim][key], swizzled
  __shared__ bf16 Pl[4 * 16 * 128];// per-wave Q staging, then P round-trip

  const int qt = blockIdx.x, h = blockIdx.y;
  const int t = threadIdx.x, w = t >> 6, l = t & 63;
  const int lr = l & 15, lq = l >> 4;
  const float NEG_INF = -__builtin_inff();
  bf16* Pw = Pl + (w << 11);       // this wave's 16x128 region

  // --- stage Q (swizzled) into Pw; hoist A-fragments ---
  {
    const int c8 = l & 15, rsub = l >> 4;
    for (int i = 0; i < 4; i++) {
      const int row = i * 4 + rsub;  // 0..15 within wave's q-rows
      const bf16x8 v = *(const bf16x8*)&qb[(size_t)(qt * 64 + w * 16 + row) * HDIM + h * 128 + c8 * 8];
      *(bf16x8*)&Pw[row * 128 + ((c8 ^ row) << 3)] = v;
    }
  }
  bf16x8 aq[4];
  for (int ks = 0; ks < 4; ks++)
    aq[ks] = *(const bf16x8*)&Pw[lr * 128 + (((ks * 4 + lq) ^ lr) << 3)];

  f32x4 o[8];
  for (int ni = 0; ni < 8; ni++)
    for (int r = 0; r < 4; r++) o[ni][r] = 0.f;
  float m_i[4], l_i[4];
  int qrow[4];
  for (int r = 0; r < 4; r++) {
    m_i[r] = NEG_INF; l_i[r] = 0.f;
    qrow[r] = qt * 64 + w * 16 + lq * 4 + r;
  }
  const float scl = 0.08838834764831845f;  // 1/sqrt(128)

  const int c8 = l & 15;
  const int rsub = (w << 2) + (l >> 4);  // 0..15

  for (int kbk = 0; kbk < 16; kbk++) {
    // --- stage K-tile and V-tile (regs -> swizzled LDS) ---
    bf16x8 kreg[8], vreg[8];
    for (int i = 0; i < 8; i++) {
      const int row = (i << 4) + rsub;
      kreg[i] = *(const bf16x8*)&kb[(size_t)(kbk * 128 + row) * HDIM + h * 128 + c8 * 8];
      vreg[i] = *(const bf16x8*)&vT[(size_t)(h * 128 + row) * HDIM + kbk * 128 + c8 * 8];
    }
    for (int i = 0; i < 8; i++) {
      const int row = (i << 4) + rsub;
      const int p8 = (c8 ^ (row & 15)) << 3;
      *(bf16x8*)&Kl[row * 128 + p8] = kreg[i];
      *(bf16x8*)&Vl[row * 128 + p8] = vreg[i];
    }
    __syncthreads();

    // --- S = Q @ K^T (wave: 16 q-rows x 128 keys) ---
    f32x4 s[8];
    for (int ni = 0; ni < 8; ni++)
      for (int r = 0; r < 4; r++) s[ni][r] = 0.f;
    for (int ks = 0; ks < 4; ks++) {
      bf16x8 bk[8];
      for (int ni = 0; ni < 8; ni++)
        bk[ni] = *(const bf16x8*)&Kl[(ni * 16 + lr) * 128 + (((ks * 4 + lq) ^ lr) << 3)];
      for (int ni = 0; ni < 8; ni++) s[ni] = MFMA16(aq[ks], bk[ni], s[ni]);
    }

    // --- scale + mask + online softmax (per-lane rows = lq*4+r) ---
    for (int ni = 0; ni < 8; ni++) {
      const int col = kbk * 128 + ni * 16 + lr;
      const bool valid = (amask[col] != 0);
      for (int r = 0; r < 4; r++) {
        float v = s[ni][r] * scl;
        if (!valid || col == qrow[r]) v = NEG_INF;
        s[ni][r] = v;
      }
    }
    float alpha[4];
    for (int r = 0; r < 4; r++) {
      float mx = NEG_INF;
      for (int ni = 0; ni < 8; ni++) mx = fmaxf(mx, s[ni][r]);
      for (int off = 1; off < 16; off <<= 1) mx = fmaxf(mx, __shfl_xor(mx, off));
      const float mold = m_i[r];
      const float mnew = fmaxf(mold, mx);
      const float a = (mold == NEG_INF) ? 0.f : __expf(mold - mnew);
      float rs = 0.f;
      for (int ni = 0; ni < 8; ni++) {
        const float sv = s[ni][r];
        const float p = (sv == NEG_INF) ? 0.f : __expf(sv - mnew);
        s[ni][r] = p;
        rs += p;
      }
      for (int off = 1; off < 16; off <<= 1) rs += __shfl_xor(rs, off);
      l_i[r] = l_i[r] * a + rs;
      m_i[r] = mnew;
      alpha[r] = a;
    }
    for (int ni = 0; ni < 8; ni++)
      for (int r = 0; r < 4; r++) o[ni][r] *= alpha[r];

    // --- P: C-layout regs -> wave-private swizzled LDS ---
    for (int ni = 0; ni < 8; ni++)
      for (int r = 0; r < 4; r++) {
        const int row = lq * 4 + r;
        Pw[row * 128 + (((ni * 2 + (lr >> 3)) ^ row) << 3) + (lr & 7)] = (bf16)s[ni][r];
      }

    // --- O += P @ V ---
    for (int ks = 0; ks < 4; ks++) {
      bf16x8 bv[8];
      for (int ni = 0; ni < 8; ni++)
        bv[ni] = *(const bf16x8*)&Vl[(ni * 16 + lr) * 128 + (((ks * 4 + lq) ^ lr) << 3)];
      const bf16x8 ap = *(const bf16x8*)&Pw[lr * 128 + (((ks * 4 + lq) ^ lr) << 3)];
      for (int ni = 0; ni < 8; ni++) o[ni] = MFMA16(ap, bv[ni], o[ni]);
    }
    __syncthreads();
  }

  // --- epilogue: ctx = O / l (fully-masked row -> 0) ---
  for (int ni = 0; ni < 8; ni++)
    for (int r = 0; r < 4; r++) {
      const int row = qrow[r];
      const int col = h * 128 + ni * 16 + lr;
      const float li = l_i[r];
      ctx[(size_t)row * HDIM + col] = (bf16)((li > 0.f) ? o[ni][r] / li : 0.f);
    }
}

// out = fp32( hs + sigmoid(scale) * (ctx @ Wo^T) )
__global__ __launch_bounds__(256) void out_gemm(
    const bf16* __restrict__ ctx, const bf16* __restrict__ Wo,
    const float* __restrict__ hs, const float* __restrict__ scale_p,
    float* __restrict__ outp) {
  __shared__ bf16 ldsA[128 * 32];
  __shared__ bf16 ldsB[128 * 32];
  const int rowBase = blockIdx.y << 7, colBase = blockIdx.x << 7;
  f32x4 acc[4][4];
  gemm128_core(ctx, Wo, rowBase, colBase, acc, ldsA, ldsB);

  const float sig = 1.0f / (1.0f + __expf(-scale_p[0]));
  const int t = threadIdx.x;
  const int w = t >> 6, l = t & 63;
  const int wr = (w >> 1) << 6, wc = (w & 1) << 6;
  const int lr = l & 15, lq = l >> 4;
  for (int mi = 0; mi < 4; mi++)
    for (int ni = 0; ni < 4; ni++) {
      const int col = colBase + wc + ni * 16 + lr;
      const int row0 = rowBase + wr + mi * 16 + lq * 4;
      for (int r = 0; r < 4; r++) {
        const size_t idx = (size_t)(row0 + r) * HDIM + col;
        outp[idx] = hs[idx] + sig * acc[mi][ni][r];
      }
    }
}

extern "C" void kernel_launch(void* const* d_in, const int* in_sizes, int n_in,
                              void* d_out, int out_size, void* d_ws, size_t ws_size,
                              hipStream_t stream) {
  const float* hs = (const float*)d_in[0];
  const unsigned char* amask = (const unsigned char*)d_in[1];
  const float* Wq = (const float*)d_in[2];
  const float* Wk = (const float*)d_in[3];
  const float* Wv = (const float*)d_in[4];
  const float* Wo = (const float*)d_in[5];
  const float* scale_p = (const float*)d_in[6];
  float* outp = (float*)d_out;

  const size_t N = (size_t)HDIM * HDIM;  // 4M elems, 8MB bf16 each
  bf16* qb   = (bf16*)d_ws;
  bf16* kb   = qb + N;
  bf16* vT   = kb + N;
  bf16* ctx  = vT + N;
  bf16* hs16 = ctx + N;
  bf16* Wq16 = hs16 + N;
  bf16* Wk16 = Wq16 + N;
  bf16* Wv16 = Wk16 + N;
  bf16* Wo16 = Wv16 + N;   // total 72 MB of d_ws

  cvt5<<<dim3(1024, 5), 256, 0, stream>>>(hs, Wq, Wk, Wv, Wo,
                                          hs16, Wq16, Wk16, Wv16, Wo16);
  qkv_gemm<<<dim3(16, 16, 3), 256, 0, stream>>>(hs16, Wq16, Wk16, Wv16, qb, kb, vT);
  attn_kernel<<<dim3(32, 16), 256, 0, stream>>>(qb, kb, vT, amask, ctx);
  out_gemm<<<dim3(16, 16), 256, 0, stream>>>(ctx, Wo16, hs, scale_p, outp);
}